// Round 4
// baseline (184.304 us; speedup 1.0000x reference)
//
#include <hip/hip_runtime.h>
#include <hip/hip_bf16.h>

typedef unsigned short ushort_t;
typedef __attribute__((ext_vector_type(8))) short short8;
typedef __attribute__((ext_vector_type(8))) unsigned short u16x8;
typedef __attribute__((ext_vector_type(4))) float f32x4;

#define BETA 0.4f
#define EPS_C 0.05f
#define NB 8192
#define NH 1024
#define NL 2048
#define NC 5

static __device__ __forceinline__ float b2f(unsigned short u) {
    union { unsigned int i; float f; } x; x.i = ((unsigned int)u) << 16; return x.f;
}
static __device__ __forceinline__ unsigned short f2b(float f) {
    union { float f; unsigned int i; } x; x.f = f;
    unsigned int i = x.i;
    unsigned int r = (i + 0x7FFFu + ((i >> 16) & 1u)) >> 16;
    return (unsigned short)r;
}

static __device__ __forceinline__ void gload16(const ushort_t* g, ushort_t* l) {
    __builtin_amdgcn_global_load_lds((const __attribute__((address_space(1))) void*)g,
                                     (__attribute__((address_space(3))) void*)l, 16, 0, 0);
}

#define CFENCE() asm volatile("" ::: "memory")
#define MFMA16(d, a, b) __builtin_amdgcn_mfma_f32_16x16x32_bf16(a, b, d, 0, 0, 0)

// ---------------- conversion kernels ----------------
__global__ __launch_bounds__(256) void cvt_kernel(const float* __restrict__ in,
                                                  ushort_t* __restrict__ out, long n) {
    long i = ((long)blockIdx.x * 256 + threadIdx.x) * 8;
    if (i >= n) return;
    const float4 a = *(const float4*)(in + i);
    const float4 b = *(const float4*)(in + i + 4);
    u16x8 o;
    o[0] = f2b(a.x); o[1] = f2b(a.y); o[2] = f2b(a.z); o[3] = f2b(a.w);
    o[4] = f2b(b.x); o[5] = f2b(b.y); o[6] = f2b(b.z); o[7] = f2b(b.w);
    *(u16x8*)(out + i) = o;
}

// W1 [2048,1024] -> W1T bf16 [1024,2048]
__global__ __launch_bounds__(256) void trans_kernel(const float* __restrict__ W1,
                                                    ushort_t* __restrict__ W1Tb) {
    __shared__ float tile[32][33];
    const int tx = threadIdx.x & 31, ty = threadIdx.x >> 5;
    const int k0 = blockIdx.x * 32, n0 = blockIdx.y * 32;
#pragma unroll
    for (int i = 0; i < 4; ++i)
        tile[ty + i * 8][tx] = W1[(size_t)(k0 + ty + i * 8) * NH + n0 + tx];
    __syncthreads();
#pragma unroll
    for (int i = 0; i < 4; ++i)
        W1Tb[(size_t)(n0 + ty + i * 8) * NL + k0 + tx] = f2b(tile[tx][ty + i * 8]);
}

// ============ GEMM1: h = tanh(x @ W1T^T + b1), split-K teams, counted vmcnt ============
// A [8192,2048], Bt [1024,2048]; BM=256 BN=128 BK=64; 2 teams x 4 waves;
// wave = 64 rows x 128 cols x 32k (ks fixed per team); rows interleaved by half.
__global__ __launch_bounds__(512, 2) void gemm1_kernel(const ushort_t* __restrict__ A,
                                                       const ushort_t* __restrict__ Bt,
                                                       const float* __restrict__ b1,
                                                       ushort_t* __restrict__ hout) {
    constexpr int K = NL;        // 2048
    constexpr int NT = K / 64;   // 32
    __shared__ ushort_t AsLo[2][8192];  // rows 0..127 of A tile
    __shared__ ushort_t AsHi[2][8192];  // rows 128..255
    __shared__ ushort_t Bsh[2][8192];   // B tile 128x64

    const int tid = threadIdx.x;
    const int wv = tid >> 6, lane = tid & 63;
    const int team = wv >> 2, w = wv & 3;
    const int fr = lane & 15, fg = lane >> 4;
    const int swz = (lane & 7) << 4;
    const int cb = (team << 6) + (fg << 4);   // column byte before xor (team k-slice)
    const int xcd = blockIdx.x & 7, loc = blockIdx.x >> 3;
    const int bm0 = (xcd * 4 + (loc >> 3)) * 256;
    const int bnIdx = loc & 7;
    const int bn0 = bnIdx * 128;
    const int srow = lane >> 3, scol = ((lane & 7) ^ srow) << 3;

    auto stA = [&](ushort_t* dst, int kt, int half) {
#pragma unroll
        for (int c = 0; c < 2; ++c) {
            const int row = wv * 16 + c * 8 + srow;
            gload16(A + (size_t)(bm0 + half * 128 + row) * K + kt * 64 + scol,
                    dst + wv * 1024 + c * 512);
        }
    };
    auto stB = [&](ushort_t* dst, int kt) {
#pragma unroll
        for (int c = 0; c < 2; ++c) {
            const int row = wv * 16 + c * 8 + srow;
            gload16(Bt + (size_t)(bn0 + row) * K + kt * 64 + scol,
                    dst + wv * 1024 + c * 512);
        }
    };
    auto ldA = [&](const ushort_t* base, int fl) -> short8 {   // fl 0..1 within half
        const int rowt = w * 32 + fl * 16 + fr;
        return *(const short8*)((const char*)base + rowt * 128 + (cb ^ swz));
    };
    auto ldB = [&](const ushort_t* base, int nf) -> short8 {
        const int rowt = nf * 16 + fr;
        return *(const short8*)((const char*)base + rowt * 128 + (cb ^ swz));
    };

    f32x4 acc[4][8] = {};
    short8 bfP[8], bfQ[8];

    // prologue: B(0)->Bs0, A(0)->As0, B(1)->Bs1; drain once; preload bf for t0
    stB(Bsh[0], 0);
    stA(AsLo[0], 0, 0);
    stA(AsHi[0], 0, 1);
    stB(Bsh[1], 1);
    asm volatile("s_waitcnt vmcnt(0) lgkmcnt(0)" ::: "memory");
    CFENCE(); __builtin_amdgcn_s_barrier(); CFENCE();
#pragma unroll
    for (int nf = 0; nf < 8; ++nf) bfP[nf] = ldB(Bsh[0], nf);

#define G1TILE(BUF, BFC, BFN, TT)                                                   \
    {                                                                               \
        const int t_ = (TT);                                                        \
        const bool moreA = (t_ + 1 < NT);                                           \
        const bool moreB = (t_ + 2 < NT);                                           \
        short8 af0[2], af1[2];                                                      \
        /* phase 0: reads af(lo half) + next-tile bf lo; stage B(t+2), A0(t+1) */   \
        af0[0] = ldA(AsLo[BUF], 0); af0[1] = ldA(AsLo[BUF], 1);                     \
        if (moreA) {                                                                \
            BFN[0] = ldB(Bsh[BUF ^ 1], 0); BFN[1] = ldB(Bsh[BUF ^ 1], 1);           \
            BFN[2] = ldB(Bsh[BUF ^ 1], 2); BFN[3] = ldB(Bsh[BUF ^ 1], 3);           \
        }                                                                           \
        if (moreB) stB(Bsh[BUF], t_ + 2);                                           \
        if (moreA) stA(AsLo[BUF ^ 1], t_ + 1, 0);                                   \
        CFENCE(); __builtin_amdgcn_s_barrier(); CFENCE();                           \
        __builtin_amdgcn_s_setprio(1);                                              \
        _Pragma("unroll") for (int f2 = 0; f2 < 2; ++f2)                            \
            _Pragma("unroll") for (int nf = 0; nf < 8; ++nf)                        \
                acc[f2][nf] = MFMA16(acc[f2][nf], af0[f2], BFC[nf]);                \
        __builtin_amdgcn_s_setprio(0);                                              \
        if (moreB)      { asm volatile("s_waitcnt vmcnt(4) lgkmcnt(0)" ::: "memory"); } \
        else if (moreA) { asm volatile("s_waitcnt vmcnt(2) lgkmcnt(0)" ::: "memory"); } \
        else            { asm volatile("s_waitcnt vmcnt(0) lgkmcnt(0)" ::: "memory"); } \
        CFENCE(); __builtin_amdgcn_s_barrier(); CFENCE();                           \
        /* phase 1: reads af(hi half) + next-tile bf hi; stage A1(t+1) */           \
        af1[0] = ldA(AsHi[BUF], 0); af1[1] = ldA(AsHi[BUF], 1);                     \
        if (moreA) {                                                                \
            BFN[4] = ldB(Bsh[BUF ^ 1], 4); BFN[5] = ldB(Bsh[BUF ^ 1], 5);           \
            BFN[6] = ldB(Bsh[BUF ^ 1], 6); BFN[7] = ldB(Bsh[BUF ^ 1], 7);           \
        }                                                                           \
        if (moreA) stA(AsHi[BUF ^ 1], t_ + 1, 1);                                   \
        CFENCE(); __builtin_amdgcn_s_barrier(); CFENCE();                           \
        __builtin_amdgcn_s_setprio(1);                                              \
        _Pragma("unroll") for (int f2 = 0; f2 < 2; ++f2)                            \
            _Pragma("unroll") for (int nf = 0; nf < 8; ++nf)                        \
                acc[2 + f2][nf] = MFMA16(acc[2 + f2][nf], af1[f2], BFC[nf]);        \
        __builtin_amdgcn_s_setprio(0);                                              \
        asm volatile("s_waitcnt vmcnt(2) lgkmcnt(0)" ::: "memory");                 \
        CFENCE(); __builtin_amdgcn_s_barrier(); CFENCE();                           \
    }

#pragma unroll 1
    for (int t = 0; t < NT; t += 2) {
        G1TILE(0, bfP, bfQ, t)
        G1TILE(1, bfQ, bfP, t + 1)
    }
#undef G1TILE

    // epilogue: cross-team reduce in LDS (4 rounds of 64 rows), tanh, store
    float* red = (float*)&AsLo[0][0];   // 64x128 f32 = 32 KB
#pragma unroll
    for (int rd = 0; rd < 4; ++rd) {
        const int half = rd >> 1, wsel = rd & 1;
        __syncthreads();
        if (team == 1 && (w >> 1) == wsel) {
#pragma unroll
            for (int f2 = 0; f2 < 2; ++f2)
#pragma unroll
                for (int nf = 0; nf < 8; ++nf) {
                    const int col = nf * 16 + fr;
#pragma unroll
                    for (int r = 0; r < 4; ++r) {
                        const int lrow = (w & 1) * 32 + f2 * 16 + fg * 4 + r;
                        red[lrow * 128 + (col ^ ((fg & 1) << 4))] = acc[half * 2 + f2][nf][r];
                    }
                }
        }
        __syncthreads();
        if (team == 0 && (w >> 1) == wsel) {
#pragma unroll
            for (int f2 = 0; f2 < 2; ++f2)
#pragma unroll
                for (int nf = 0; nf < 8; ++nf) {
                    const int col = nf * 16 + fr;
                    const float bb = b1[bn0 + col];
#pragma unroll
                    for (int r = 0; r < 4; ++r) {
                        const int lrow = (w & 1) * 32 + f2 * 16 + fg * 4 + r;
                        const float s = acc[half * 2 + f2][nf][r] +
                                        red[lrow * 128 + (col ^ ((fg & 1) << 4))];
                        const int grow = bm0 + half * 128 + w * 32 + f2 * 16 + fg * 4 + r;
                        hout[(size_t)grow * NH + bn0 + col] = f2b(tanhf(s + bb));
                    }
                }
        }
    }
}

// ============ GEMM2: row L1 partials of v @ W1b^T, 256x256, counted vmcnt ============
// A [8192,1024], Bt [2048,1024]; 8 waves 2Mx4N; wave = 128 rows x 64 cols (interleaved halves)
__global__ __launch_bounds__(512, 2) void gemm2_kernel(const ushort_t* __restrict__ A,
                                                       const ushort_t* __restrict__ Bt,
                                                       float* __restrict__ partout) {
    constexpr int K = NH;        // 1024
    constexpr int NT = K / 64;   // 16
    __shared__ ushort_t AsLo[2][8192];
    __shared__ ushort_t AsHi[2][8192];
    __shared__ ushort_t BsLo[2][8192];
    __shared__ ushort_t BsHi[2][8192];

    const int tid = threadIdx.x;
    const int wv = tid >> 6, lane = tid & 63;
    const int wm = wv >> 2, wn = wv & 3;
    const int fr = lane & 15, fg = lane >> 4;
    const int swz = (lane & 7) << 4;
    const int cbb = fg << 4;
    const int xcd = blockIdx.x & 7, loc = blockIdx.x >> 3;
    const int bm0 = (xcd * 4 + (loc >> 3)) * 256;
    const int bnIdx = loc & 7;
    const int bn0 = bnIdx * 256;
    const int srow = lane >> 3, scol = ((lane & 7) ^ srow) << 3;

    auto stA = [&](ushort_t* dst, int kt, int half) {
#pragma unroll
        for (int c = 0; c < 2; ++c) {
            const int row = wv * 16 + c * 8 + srow;
            gload16(A + (size_t)(bm0 + half * 128 + row) * K + kt * 64 + scol,
                    dst + wv * 1024 + c * 512);
        }
    };
    auto stB = [&](ushort_t* dst, int kt, int half) {
#pragma unroll
        for (int c = 0; c < 2; ++c) {
            const int row = wv * 16 + c * 8 + srow;
            gload16(Bt + (size_t)(bn0 + half * 128 + row) * K + kt * 64 + scol,
                    dst + wv * 1024 + c * 512);
        }
    };
    auto ldA = [&](const ushort_t* base, int i, int ks) -> short8 {
        const int rowt = wm * 64 + i * 16 + fr;
        return *(const short8*)((const char*)base + rowt * 128 + (((ks << 6) + cbb) ^ swz));
    };
    auto ldB = [&](const ushort_t* base, int n, int ks) -> short8 {
        const int rowt = wn * 32 + n * 16 + fr;
        return *(const short8*)((const char*)base + rowt * 128 + (((ks << 6) + cbb) ^ swz));
    };

    f32x4 acc[8][4] = {};
    short8 bfL[2][2], bfH[2][2];

    // prologue: stage B0,A0,A1,B1 of tile 0; counted wait; preload bfL
    stB(BsLo[0], 0, 0);
    stA(AsLo[0], 0, 0);
    stA(AsHi[0], 0, 1);
    stB(BsHi[0], 0, 1);
    asm volatile("s_waitcnt vmcnt(4) lgkmcnt(0)" ::: "memory");
    CFENCE(); __builtin_amdgcn_s_barrier(); CFENCE();
#pragma unroll
    for (int n = 0; n < 2; ++n) {
        bfL[n][0] = ldB(BsLo[0], n, 0);
        bfL[n][1] = ldB(BsLo[0], n, 1);
    }

#define G2TILE(BUF, TT)                                                             \
    {                                                                               \
        const int t_ = (TT);                                                        \
        const bool more = (t_ + 1 < NT);                                            \
        short8 afL[4][2], afH[4][2];                                                \
        /* phase 0: rd afL; stage B0' */                                            \
        _Pragma("unroll") for (int i = 0; i < 4; ++i) {                             \
            afL[i][0] = ldA(AsLo[BUF], i, 0); afL[i][1] = ldA(AsLo[BUF], i, 1);     \
        }                                                                           \
        if (more) stB(BsLo[BUF ^ 1], t_ + 1, 0);                                    \
        CFENCE(); __builtin_amdgcn_s_barrier(); CFENCE();                           \
        __builtin_amdgcn_s_setprio(1);                                              \
        _Pragma("unroll") for (int i = 0; i < 4; ++i)                               \
            _Pragma("unroll") for (int n = 0; n < 2; ++n) {                         \
                acc[i][n] = MFMA16(acc[i][n], afL[i][0], bfL[n][0]);                \
                acc[i][n] = MFMA16(acc[i][n], afL[i][1], bfL[n][1]);                \
            }                                                                       \
        __builtin_amdgcn_s_setprio(0);                                              \
        if (more) { asm volatile("s_waitcnt vmcnt(4) lgkmcnt(0)" ::: "memory"); }   \
        else      { asm volatile("s_waitcnt vmcnt(2) lgkmcnt(0)" ::: "memory"); }   \
        CFENCE(); __builtin_amdgcn_s_barrier(); CFENCE();                           \
        /* phase 1: rd afH; stage A0' */                                            \
        _Pragma("unroll") for (int i = 0; i < 4; ++i) {                             \
            afH[i][0] = ldA(AsHi[BUF], i, 0); afH[i][1] = ldA(AsHi[BUF], i, 1);     \
        }                                                                           \
        if (more) stA(AsLo[BUF ^ 1], t_ + 1, 0);                                    \
        CFENCE(); __builtin_amdgcn_s_barrier(); CFENCE();                           \
        __builtin_amdgcn_s_setprio(1);                                              \
        _Pragma("unroll") for (int i = 0; i < 4; ++i)                               \
            _Pragma("unroll") for (int n = 0; n < 2; ++n) {                         \
                acc[4 + i][n] = MFMA16(acc[4 + i][n], afH[i][0], bfL[n][0]);        \
                acc[4 + i][n] = MFMA16(acc[4 + i][n], afH[i][1], bfL[n][1]);        \
            }                                                                       \
        __builtin_amdgcn_s_setprio(0);                                              \
        if (more) { asm volatile("s_waitcnt vmcnt(4) lgkmcnt(0)" ::: "memory"); }   \
        else      { asm volatile("s_waitcnt vmcnt(0) lgkmcnt(0)" ::: "memory"); }   \
        CFENCE(); __builtin_amdgcn_s_barrier(); CFENCE();                           \
        /* phase 2: rd bfH; stage A1' */                                            \
        _Pragma("unroll") for (int n = 0; n < 2; ++n) {                             \
            bfH[n][0] = ldB(BsHi[BUF], n, 0); bfH[n][1] = ldB(BsHi[BUF], n, 1);     \
        }                                                                           \
        if (more) stA(AsHi[BUF ^ 1], t_ + 1, 1);                                    \
        CFENCE(); __builtin_amdgcn_s_barrier(); CFENCE();                           \
        __builtin_amdgcn_s_setprio(1);                                              \
        _Pragma("unroll") for (int i = 0; i < 4; ++i)                               \
            _Pragma("unroll") for (int n = 0; n < 2; ++n) {                         \
                acc[i][2 + n] = MFMA16(acc[i][2 + n], afL[i][0], bfH[n][0]);        \
                acc[i][2 + n] = MFMA16(acc[i][2 + n], afL[i][1], bfH[n][1]);        \
            }                                                                       \
        __builtin_amdgcn_s_setprio(0);                                              \
        asm volatile("s_waitcnt vmcnt(4) lgkmcnt(0)" ::: "memory");                 \
        CFENCE(); __builtin_amdgcn_s_barrier(); CFENCE();                           \
        /* phase 3: rd next-tile bfL; stage B1' */                                  \
        if (more) {                                                                 \
            _Pragma("unroll") for (int n = 0; n < 2; ++n) {                         \
                bfL[n][0] = ldB(BsLo[BUF ^ 1], n, 0);                               \
                bfL[n][1] = ldB(BsLo[BUF ^ 1], n, 1);                               \
            }                                                                       \
            stB(BsHi[BUF ^ 1], t_ + 1, 1);                                          \
        }                                                                           \
        CFENCE(); __builtin_amdgcn_s_barrier(); CFENCE();                           \
        __builtin_amdgcn_s_setprio(1);                                              \
        _Pragma("unroll") for (int i = 0; i < 4; ++i)                               \
            _Pragma("unroll") for (int n = 0; n < 2; ++n) {                         \
                acc[4 + i][2 + n] = MFMA16(acc[4 + i][2 + n], afH[i][0], bfH[n][0]); \
                acc[4 + i][2 + n] = MFMA16(acc[4 + i][2 + n], afH[i][1], bfH[n][1]); \
            }                                                                       \
        __builtin_amdgcn_s_setprio(0);                                              \
        asm volatile("s_waitcnt vmcnt(4) lgkmcnt(0)" ::: "memory");                 \
        CFENCE(); __builtin_amdgcn_s_barrier(); CFENCE();                           \
    }

#pragma unroll 1
    for (int t = 0; t < NT; t += 2) {
        G2TILE(0, t)
        G2TILE(1, t + 1)
    }
#undef G2TILE

    // epilogue: per-row |.| partial sums
    float* rsum = (float*)&AsLo[0][0];
#pragma unroll
    for (int f = 0; f < 8; ++f)
#pragma unroll
        for (int r = 0; r < 4; ++r) {
            float s = 0.f;
#pragma unroll
            for (int n = 0; n < 4; ++n) s += fabsf(acc[f][n][r]);
            s += __shfl_xor(s, 1); s += __shfl_xor(s, 2);
            s += __shfl_xor(s, 4); s += __shfl_xor(s, 8);
            if (fr == 0) {
                const int rloc = (f < 4 ? wm * 64 + f * 16 : 128 + wm * 64 + (f - 4) * 16)
                                 + fg * 4 + r;
                rsum[wn * 256 + rloc] = s;
            }
        }
    __syncthreads();
    if (tid < 256)
        partout[(size_t)bnIdx * NB + bm0 + tid] =
            rsum[tid] + rsum[256 + tid] + rsum[512 + tid] + rsum[768 + tid];
}

// ---------------- per-row kernel: logits, losses, v ----------------
__global__ __launch_bounds__(256) void rows_kernel(const ushort_t* __restrict__ hb,
                                                   const int* __restrict__ y,
                                                   const float* __restrict__ W2,
                                                   const float* __restrict__ b2,
                                                   ushort_t* __restrict__ vb,
                                                   float4* __restrict__ rowstats) {
    __shared__ float w2s[NH * NC];
    __shared__ float b2s[NC];
    const int tid = threadIdx.x;
    for (int i = tid; i < NH * NC; i += 256) w2s[i] = W2[i];
    if (tid < NC) b2s[tid] = b2[tid];
    __syncthreads();
    const int wid = tid >> 6, lane = tid & 63;
    const int row = blockIdx.x * 4 + wid;
    const ushort_t* hrow = hb + (size_t)row * NH;
    ushort_t* vrow = vb + (size_t)row * NH;
    const int yi = y[row];
    float d0 = 0, d1 = 0, d2 = 0, d3 = 0, d4 = 0;
#pragma unroll
    for (int it = 0; it < 2; ++it) {
        const int n0 = it * 512 + lane * 8;
        u16x8 hv = *(const u16x8*)(hrow + n0);
        u16x8 ov;
#pragma unroll
        for (int j = 0; j < 8; ++j) {
            float hh = b2f(hv[j]);
            const float* wrow = &w2s[(n0 + j) * NC];
            d0 += hh * wrow[0]; d1 += hh * wrow[1]; d2 += hh * wrow[2];
            d3 += hh * wrow[3]; d4 += hh * wrow[4];
            ov[j] = f2b((1.f - hh * hh) * wrow[yi]);
        }
        *(u16x8*)(vrow + n0) = ov;
    }
#pragma unroll
    for (int off = 32; off; off >>= 1) {
        d0 += __shfl_xor(d0, off); d1 += __shfl_xor(d1, off); d2 += __shfl_xor(d2, off);
        d3 += __shfl_xor(d3, off); d4 += __shfl_xor(d4, off);
    }
    if (lane == 0) {
        float lg[NC] = { d0 + b2s[0], d1 + b2s[1], d2 + b2s[2], d3 + b2s[3], d4 + b2s[4] };
        float zy = lg[yi];
        float mse = 0.f, marg = 0.f;
        int amax = 0; float best = lg[0];
#pragma unroll
        for (int c = 0; c < NC; ++c) {
            float t = lg[c] - (c == yi ? 1.f : 0.f);
            mse += t * t;
            if (c != yi) marg += fmaxf(1.f - zy + lg[c], 0.f);
            if (lg[c] > best) { best = lg[c]; amax = c; }
        }
        rowstats[row] = make_float4(zy, mse, marg, (amax == yi) ? 1.f : 0.f);
    }
}

// ---------------- reductions ----------------
__global__ __launch_bounds__(256) void reduce_rows(const float4* __restrict__ rs,
                                                   const float* __restrict__ part,
                                                   int NT, float4* __restrict__ bsums) {
    const int tid = threadIdx.x;
    const int r = blockIdx.x * 256 + tid;
    float4 v = rs[r];
    float wl1 = 0.f;
    for (int t = 0; t < NT; ++t) wl1 += part[(size_t)t * NB + r];
    float R = wl1 * EPS_C / (fabsf(v.x) + 1e-8f);
    float4 s = make_float4(v.y, v.z, v.w, log1pf(R));
#pragma unroll
    for (int off = 32; off; off >>= 1) {
        s.x += __shfl_down(s.x, off); s.y += __shfl_down(s.y, off);
        s.z += __shfl_down(s.z, off); s.w += __shfl_down(s.w, off);
    }
    __shared__ float4 red[4];
    if ((tid & 63) == 0) red[tid >> 6] = s;
    __syncthreads();
    if (tid == 0) {
        float4 t = red[0];
        for (int i = 1; i < 4; ++i) { t.x += red[i].x; t.y += red[i].y; t.z += red[i].z; t.w += red[i].w; }
        bsums[blockIdx.x] = t;
    }
}

__global__ void final_combine(const float4* __restrict__ bsums, int nb, float* __restrict__ out) {
    if (threadIdx.x == 0) {
        float mse = 0, marg = 0, corr = 0, nsr = 0;
        for (int i = 0; i < nb; ++i) {
            float4 s = bsums[i];
            mse += s.x; marg += s.y; corr += s.z; nsr += s.w;
        }
        const float Bf = (float)NB;
        out[0] = mse / (Bf * (float)NC) + (marg / Bf + BETA * nsr / Bf) * (corr / Bf);
    }
}

extern "C" void kernel_launch(void* const* d_in, const int* in_sizes, int n_in,
                              void* d_out, int out_size, void* d_ws, size_t ws_size,
                              hipStream_t stream) {
    const float* x  = (const float*)d_in[0];
    const int*   y  = (const int*)d_in[1];
    const float* W1 = (const float*)d_in[2];
    const float* b1 = (const float*)d_in[3];
    const float* W2 = (const float*)d_in[4];
    const float* b2 = (const float*)d_in[5];
    float* out = (float*)d_out;

    char* ws = (char*)d_ws;
    ushort_t* W1Tb = (ushort_t*)(ws);                           // 4MB
    ushort_t* W1b  = (ushort_t*)(ws + (4ul << 20));             // 4MB
    ushort_t* xb   = (ushort_t*)(ws + (8ul << 20));             // 32MB
    ushort_t* hb   = (ushort_t*)(ws + (40ul << 20));            // 16MB
    ushort_t* vb   = (ushort_t*)(ws + (56ul << 20));            // 16MB
    float4*   rowstats = (float4*)(ws + (72ul << 20));          // 128KB
    float*    part = (float*)(ws + (72ul << 20) + (1ul << 20)); // 256KB
    float4*   bsums = (float4*)(ws + (74ul << 20));             // 512B

    // 1. conversions
    cvt_kernel<<<(NB * (long)NL) / (256 * 8), 256, 0, stream>>>(x, xb, (long)NB * NL);
    cvt_kernel<<<(NL * (long)NH) / (256 * 8), 256, 0, stream>>>(W1, W1b, (long)NL * NH);
    trans_kernel<<<dim3(NL / 32, NH / 32), 256, 0, stream>>>(W1, W1Tb);

    // 2. GEMM1: h = tanh(x @ W1 + b1)  [8192x1024]
    gemm1_kernel<<<256, 512, 0, stream>>>(xb, W1Tb, b1, hb);

    // 3. per-row: logits/mse/margin/zy/correct + v
    rows_kernel<<<NB / 4, 256, 0, stream>>>(hb, y, W2, b2, vb, rowstats);

    // 4. GEMM2: g = v @ W1^T, row |.| partials  [8192x2048]
    gemm2_kernel<<<256, 512, 0, stream>>>(vb, W1b, part);

    // 5. reductions
    reduce_rows<<<NB / 256, 256, 0, stream>>>(rowstats, part, NL / 256, bsums);
    final_combine<<<1, 64, 0, stream>>>(bsums, NB / 256, out);
}

// Round 5
// 144.087 us; speedup vs baseline: 1.2791x; 1.2791x over previous
//
#include <hip/hip_runtime.h>
#include <hip/hip_bf16.h>

typedef unsigned short ushort_t;
typedef __attribute__((ext_vector_type(8))) short short8;
typedef __attribute__((ext_vector_type(8))) unsigned short u16x8;
typedef __attribute__((ext_vector_type(4))) float f32x4;

#define BETA 0.4f
#define EPS_C 0.05f
#define NB 8192
#define NH 1024
#define NL 2048
#define NC 5

static __device__ __forceinline__ float b2f(unsigned short u) {
    union { unsigned int i; float f; } x; x.i = ((unsigned int)u) << 16; return x.f;
}
static __device__ __forceinline__ unsigned short f2b(float f) {
    union { float f; unsigned int i; } x; x.f = f;
    unsigned int i = x.i;
    unsigned int r = (i + 0x7FFFu + ((i >> 16) & 1u)) >> 16;
    return (unsigned short)r;
}

static __device__ __forceinline__ void gload16(const ushort_t* g, ushort_t* l) {
    __builtin_amdgcn_global_load_lds((const __attribute__((address_space(1))) void*)g,
                                     (__attribute__((address_space(3))) void*)l, 16, 0, 0);
}

#define CFENCE() asm volatile("" ::: "memory")
#define MFMA16(d, a, b) __builtin_amdgcn_mfma_f32_16x16x32_bf16(a, b, d, 0, 0, 0)

// ---------------- conversion kernels ----------------
__global__ __launch_bounds__(256) void cvt_kernel(const float* __restrict__ in,
                                                  ushort_t* __restrict__ out, long n) {
    long i = ((long)blockIdx.x * 256 + threadIdx.x) * 8;
    if (i >= n) return;
    const float4 a = *(const float4*)(in + i);
    const float4 b = *(const float4*)(in + i + 4);
    u16x8 o;
    o[0] = f2b(a.x); o[1] = f2b(a.y); o[2] = f2b(a.z); o[3] = f2b(a.w);
    o[4] = f2b(b.x); o[5] = f2b(b.y); o[6] = f2b(b.z); o[7] = f2b(b.w);
    *(u16x8*)(out + i) = o;
}

// W1 [2048,1024] -> W1T bf16 [1024,2048]
__global__ __launch_bounds__(256) void trans_kernel(const float* __restrict__ W1,
                                                    ushort_t* __restrict__ W1Tb) {
    __shared__ float tile[32][33];
    const int tx = threadIdx.x & 31, ty = threadIdx.x >> 5;
    const int k0 = blockIdx.x * 32, n0 = blockIdx.y * 32;
#pragma unroll
    for (int i = 0; i < 4; ++i)
        tile[ty + i * 8][tx] = W1[(size_t)(k0 + ty + i * 8) * NH + n0 + tx];
    __syncthreads();
#pragma unroll
    for (int i = 0; i < 4; ++i)
        W1Tb[(size_t)(n0 + ty + i * 8) * NL + k0 + tx] = f2b(tile[tx][ty + i * 8]);
}

// ---------------- GEMM1: round-3 proven structure (gemm8p<0>) ----------------
template <int EPI>
__global__ __launch_bounds__(512, 2) void gemm8p(const ushort_t* __restrict__ A,
                                                 const ushort_t* __restrict__ Bt,
                                                 const float* __restrict__ b1,
                                                 ushort_t* __restrict__ hout,
                                                 float* __restrict__ partout) {
    constexpr int BN_T = (EPI == 0) ? 128 : 256;
    constexpr int K    = (EPI == 0) ? 2048 : 1024;
    constexpr int NOUT = (EPI == 0) ? 1024 : 2048;
    constexpr int NT   = K / 64;
    constexpr int NPH  = (EPI == 0) ? 2 : 4;
    constexpr int MPP  = 8 / NPH;
    constexpr int NREP = BN_T / 64;

    __shared__ ushort_t As[2][16384];
    __shared__ ushort_t Bs[2][BN_T * 64];

    const int tid = threadIdx.x;
    const int wv = tid >> 6, lane = tid & 63;
    const int wm = wv >> 2, wn = wv & 3;
    const int fr = lane & 15, fg = lane >> 4;
    const int swz = (lane & 7) << 4;
    const int cbb = fg << 4;

    const int xcd = blockIdx.x & 7, loc = blockIdx.x >> 3;
    const int bm0 = (xcd * 4 + (loc >> 3)) * 256;
    const int bnIdx = loc & 7;
    const int bn0 = bnIdx * BN_T;

    const int srow = lane >> 3;
    const int scol = ((lane & 7) ^ srow) << 3;

    auto stA = [&](int buf, int kt, int half) {
#pragma unroll
        for (int c = 0; c < 2; ++c) {
            const int row = wv * 16 + c * 8 + srow;
            gload16(A + (size_t)(bm0 + half * 128 + row) * K + kt * 64 + scol,
                    &As[buf][half * 8192 + wv * 1024 + c * 512]);
        }
    };
    auto stB = [&](int buf, int kt, int half) {
#pragma unroll
        for (int c = 0; c < 2; ++c) {
            const int row = wv * 16 + c * 8 + srow;
            gload16(Bt + (size_t)(bn0 + half * 128 + row) * K + kt * 64 + scol,
                    &Bs[buf][half * 8192 + wv * 1024 + c * 512]);
        }
    };
    auto ldA = [&](int buf, int mf, int ks) -> short8 {
        const int rowt = wm * 128 + mf * 16 + fr;
        return *(const short8*)((const char*)&As[buf][0] + rowt * 128 + (((ks << 6) + cbb) ^ swz));
    };
    auto ldB = [&](int buf, int nf, int ks) -> short8 {
        const int rowt = wn * (BN_T / 4) + nf * 16 + fr;
        return *(const short8*)((const char*)&Bs[buf][0] + rowt * 128 + (((ks << 6) + cbb) ^ swz));
    };

    f32x4 acc[8][NREP] = {};

    stA(0, 0, 0); stA(0, 0, 1);
    stB(0, 0, 0);
    if constexpr (EPI == 1) stB(0, 0, 1);
    asm volatile("s_waitcnt vmcnt(0)" ::: "memory");
    CFENCE(); __builtin_amdgcn_s_barrier(); CFENCE();

#define TILEBODY(BUF, TT)                                                          \
    {                                                                              \
        const int ttv = (TT);                                                      \
        const bool more = ttv + 1 < NT;                                            \
        short8 bfl[NREP][2];                                                       \
        _Pragma("unroll")                                                          \
        for (int n = 0; n < NREP; ++n) {                                           \
            bfl[n][0] = ldB(BUF, n, 0);                                            \
            bfl[n][1] = ldB(BUF, n, 1);                                            \
        }                                                                          \
        _Pragma("unroll")                                                          \
        for (int p = 0; p < NPH; ++p) {                                            \
            short8 af[MPP][2];                                                     \
            _Pragma("unroll")                                                      \
            for (int i = 0; i < MPP; ++i) {                                        \
                af[i][0] = ldA(BUF, p * MPP + i, 0);                               \
                af[i][1] = ldA(BUF, p * MPP + i, 1);                               \
            }                                                                      \
            if (p == 0 && more) {                                                  \
                stA(BUF ^ 1, ttv + 1, 0);                                          \
                stA(BUF ^ 1, ttv + 1, 1);                                          \
                if constexpr (EPI == 0) stB(BUF ^ 1, ttv + 1, 0);                  \
            }                                                                      \
            if constexpr (EPI == 1)                                                \
                if (p == 1 && more) {                                              \
                    stB(BUF ^ 1, ttv + 1, 0);                                      \
                    stB(BUF ^ 1, ttv + 1, 1);                                      \
                }                                                                  \
            CFENCE(); __builtin_amdgcn_s_barrier(); CFENCE();                      \
            __builtin_amdgcn_s_setprio(1);                                         \
            _Pragma("unroll")                                                      \
            for (int i = 0; i < MPP; ++i) {                                        \
                _Pragma("unroll")                                                  \
                for (int n = 0; n < NREP; ++n) {                                   \
                    acc[p * MPP + i][n] = __builtin_amdgcn_mfma_f32_16x16x32_bf16( \
                        af[i][0], bfl[n][0], acc[p * MPP + i][n], 0, 0, 0);        \
                    acc[p * MPP + i][n] = __builtin_amdgcn_mfma_f32_16x16x32_bf16( \
                        af[i][1], bfl[n][1], acc[p * MPP + i][n], 0, 0, 0);        \
                }                                                                  \
            }                                                                      \
            __builtin_amdgcn_s_setprio(0);                                         \
            if (p == NPH - 1) asm volatile("s_waitcnt vmcnt(0)" ::: "memory");     \
            CFENCE(); __builtin_amdgcn_s_barrier(); CFENCE();                      \
        }                                                                          \
    }

#pragma unroll 1
    for (int t = 0; t < NT; t += 2) {
        TILEBODY(0, t)
        TILEBODY(1, t + 1)
    }
#undef TILEBODY

    if constexpr (EPI == 0) {
#pragma unroll
        for (int m = 0; m < 8; ++m)
#pragma unroll
            for (int n = 0; n < NREP; ++n) {
                const int col = bn0 + wn * 32 + n * 16 + fr;
                const float bb = b1[col];
                const size_t rbase = (size_t)(bm0 + wm * 128 + m * 16 + fg * 4) * NOUT + col;
#pragma unroll
                for (int r = 0; r < 4; ++r)
                    hout[rbase + (size_t)r * NOUT] = f2b(tanhf(acc[m][n][r] + bb));
            }
    } else {
        float* rsum = (float*)&As[0][0];
#pragma unroll
        for (int m = 0; m < 8; ++m)
#pragma unroll
            for (int r = 0; r < 4; ++r) {
                float s = 0.f;
#pragma unroll
                for (int n = 0; n < NREP; ++n) s += fabsf(acc[m][n][r]);
                s += __shfl_xor(s, 1); s += __shfl_xor(s, 2);
                s += __shfl_xor(s, 4); s += __shfl_xor(s, 8);
                if (fr == 0) rsum[wn * 256 + wm * 128 + m * 16 + fg * 4 + r] = s;
            }
        __syncthreads();
        if (tid < 256)
            partout[(size_t)bnIdx * NB + bm0 + tid] =
                rsum[tid] + rsum[256 + tid] + rsum[512 + tid] + rsum[768 + tid];
    }
}

// ---------------- GEMM2: ring-scheduled 256x256, one counted vmcnt per tile ----------------
// A [8192,1024] bf16, Bt [2048,1024] bf16. Output: per-row |.| partials.
// LDS halves: Alo/Ahi = rows 0-127/128-255 x 64k (128B rows, XOR swizzle);
//             Bk0/Bk1 = 256 n-rows x k-half 32 (packed 2 rows per 128B, swizzled).
__global__ __launch_bounds__(512, 2) void gemm2_ring(const ushort_t* __restrict__ A,
                                                     const ushort_t* __restrict__ Bt,
                                                     float* __restrict__ partout) {
    constexpr int K = NH;        // 1024
    constexpr int NT = K / 64;   // 16
    __shared__ ushort_t Alo[2][8192];
    __shared__ ushort_t Ahi[2][8192];
    __shared__ ushort_t Bk0[2][8192];
    __shared__ ushort_t Bk1[2][8192];

    const int tid = threadIdx.x;
    const int wv = tid >> 6, lane = tid & 63;
    const int wm = wv >> 2, wn = wv & 3;       // 2M x 4N waves, wave tile 128x64
    const int fr = lane & 15, fg = lane >> 4;
    const int xcd = blockIdx.x & 7, loc = blockIdx.x >> 3;
    const int bm0 = (xcd * 4 + (loc >> 3)) * 256;
    const int bnIdx = loc & 7;
    const int bn0 = bnIdx * 256;

    // A staging: linear dest, inverse-swizzled source (full-BK 128B rows)
    auto stA = [&](ushort_t* dst, int kt, int half) {
#pragma unroll
        for (int c = 0; c < 2; ++c) {
            const int rowl = c * 64 + (tid >> 3);
            const int kc = (((tid & 7) ^ (rowl & 7)) << 3);
            gload16(A + (size_t)(bm0 + half * 128 + rowl) * K + kt * 64 + kc,
                    dst + c * 4096 + tid * 8);
        }
    };
    // B staging: packed layout, slot sl = ((n&1)<<2)|kchunk, phys = sl ^ (row128&7)
    auto stB = [&](ushort_t* dst, int kt, int kh) {
#pragma unroll
        for (int c = 0; c < 2; ++c) {
            const int r1 = c * 64 + (tid >> 3);
            const int sl = (tid & 7) ^ (r1 & 7);
            const int n = r1 * 2 + (sl >> 2);
            const int kc = kh * 32 + ((sl & 3) << 3);
            gload16(Bt + (size_t)(bn0 + n) * K + kt * 64 + kc,
                    dst + c * 4096 + tid * 8);
        }
    };
    auto ldA = [&](const ushort_t* base, int mf, int ks) -> short8 {
        const int rowl = mf * 16 + fr;
        return *(const short8*)((const char*)base + rowl * 128 +
                                (((ks << 6) + (fg << 4)) ^ ((rowl & 7) << 4)));
    };
    auto ldB = [&](const ushort_t* base, int nf) -> short8 {
        const int n = wn * 64 + nf * 16 + fr;
        const int r1 = n >> 1;
        const int sl = ((n & 1) << 2) | fg;
        return *(const short8*)((const char*)base + r1 * 128 + ((sl ^ (r1 & 7)) << 4));
    };

    f32x4 acc[8][4] = {};

    // prologue: stage tile 0's four halves (no wait -- t0.p0's vmcnt(4) covers them)
    stA(&Alo[0][0], 0, 0); stB(&Bk0[0][0], 0, 0);
    stA(&Ahi[0][0], 0, 1); stB(&Bk1[0][0], 0, 1);

#define RTILE(BUF, TT)                                                              \
    {                                                                               \
        const int t_ = (TT);                                                        \
        const bool more = (t_ + 1 < NT);                                            \
        const ushort_t* Ah = wm ? &Ahi[BUF][0] : &Alo[BUF][0];                      \
        short8 af0[8], af1[8], bfa[2], bfb[2];                                      \
        /* ---- p0: stage Alo',Bk0'; ONE counted wait; reads A ks0 + Bk0 n01 */     \
        if (more) {                                                                 \
            stA(&Alo[BUF ^ 1][0], t_ + 1, 0);                                       \
            stB(&Bk0[BUF ^ 1][0], t_ + 1, 0);                                       \
            asm volatile("s_waitcnt vmcnt(4)" ::: "memory");                        \
        } else {                                                                    \
            asm volatile("s_waitcnt vmcnt(0)" ::: "memory");                        \
        }                                                                           \
        CFENCE(); __builtin_amdgcn_s_barrier(); CFENCE();                           \
        _Pragma("unroll") for (int m = 0; m < 8; ++m) af0[m] = ldA(Ah, m, 0);       \
        bfa[0] = ldB(&Bk0[BUF][0], 0); bfa[1] = ldB(&Bk0[BUF][0], 1);               \
        __builtin_amdgcn_s_setprio(1);                                              \
        _Pragma("unroll") for (int m = 0; m < 8; ++m) {                             \
            acc[m][0] = MFMA16(acc[m][0], af0[m], bfa[0]);                          \
            acc[m][1] = MFMA16(acc[m][1], af0[m], bfa[1]);                          \
        }                                                                           \
        __builtin_amdgcn_s_setprio(0);                                              \
        CFENCE(); __builtin_amdgcn_s_barrier(); CFENCE();                           \
        /* ---- p1: reads Bk0 n23; stage Ahi',Bk1' */                               \
        bfb[0] = ldB(&Bk0[BUF][0], 2); bfb[1] = ldB(&Bk0[BUF][0], 3);               \
        if (more) {                                                                 \
            stA(&Ahi[BUF ^ 1][0], t_ + 1, 1);                                       \
            stB(&Bk1[BUF ^ 1][0], t_ + 1, 1);                                       \
        }                                                                           \
        CFENCE(); __builtin_amdgcn_s_barrier(); CFENCE();                           \
        __builtin_amdgcn_s_setprio(1);                                              \
        _Pragma("unroll") for (int m = 0; m < 8; ++m) {                             \
            acc[m][2] = MFMA16(acc[m][2], af0[m], bfb[0]);                          \
            acc[m][3] = MFMA16(acc[m][3], af0[m], bfb[1]);                          \
        }                                                                           \
        __builtin_amdgcn_s_setprio(0);                                              \
        CFENCE(); __builtin_amdgcn_s_barrier(); CFENCE();                           \
        /* ---- p2: reads A ks1 + Bk1 n01 */                                        \
        _Pragma("unroll") for (int m = 0; m < 8; ++m) af1[m] = ldA(Ah, m, 1);       \
        bfa[0] = ldB(&Bk1[BUF][0], 0); bfa[1] = ldB(&Bk1[BUF][0], 1);               \
        CFENCE(); __builtin_amdgcn_s_barrier(); CFENCE();                           \
        __builtin_amdgcn_s_setprio(1);                                              \
        _Pragma("unroll") for (int m = 0; m < 8; ++m) {                             \
            acc[m][0] = MFMA16(acc[m][0], af1[m], bfa[0]);                          \
            acc[m][1] = MFMA16(acc[m][1], af1[m], bfa[1]);                          \
        }                                                                           \
        __builtin_amdgcn_s_setprio(0);                                              \
        CFENCE(); __builtin_amdgcn_s_barrier(); CFENCE();                           \
        /* ---- p3: reads Bk1 n23 */                                                \
        bfb[0] = ldB(&Bk1[BUF][0], 2); bfb[1] = ldB(&Bk1[BUF][0], 3);               \
        CFENCE(); __builtin_amdgcn_s_barrier(); CFENCE();                           \
        __builtin_amdgcn_s_setprio(1);                                              \
        _Pragma("unroll") for (int m = 0; m < 8; ++m) {                             \
            acc[m][2] = MFMA16(acc[m][2], af1[m], bfb[0]);                          \
            acc[m][3] = MFMA16(acc[m][3], af1[m], bfb[1]);                          \
        }                                                                           \
        __builtin_amdgcn_s_setprio(0);                                              \
        CFENCE(); __builtin_amdgcn_s_barrier(); CFENCE();                           \
    }

#pragma unroll 1
    for (int t = 0; t < NT; t += 2) {
        RTILE(0, t)
        RTILE(1, t + 1)
    }
#undef RTILE

    // epilogue: per-row |.| partial sums
    float* rsum = (float*)&Alo[0][0];
#pragma unroll
    for (int m = 0; m < 8; ++m)
#pragma unroll
        for (int r = 0; r < 4; ++r) {
            float s = 0.f;
#pragma unroll
            for (int n = 0; n < 4; ++n) s += fabsf(acc[m][n][r]);
            s += __shfl_xor(s, 1); s += __shfl_xor(s, 2);
            s += __shfl_xor(s, 4); s += __shfl_xor(s, 8);
            if (fr == 0) rsum[wn * 256 + wm * 128 + m * 16 + fg * 4 + r] = s;
        }
    __syncthreads();
    if (tid < 256)
        partout[(size_t)bnIdx * NB + bm0 + tid] =
            rsum[tid] + rsum[256 + tid] + rsum[512 + tid] + rsum[768 + tid];
}

// ---------------- per-row kernel: logits, losses, v ----------------
__global__ __launch_bounds__(256) void rows_kernel(const ushort_t* __restrict__ hb,
                                                   const int* __restrict__ y,
                                                   const float* __restrict__ W2,
                                                   const float* __restrict__ b2,
                                                   ushort_t* __restrict__ vb,
                                                   float4* __restrict__ rowstats) {
    __shared__ float w2s[NH * NC];
    __shared__ float b2s[NC];
    const int tid = threadIdx.x;
    for (int i = tid; i < NH * NC; i += 256) w2s[i] = W2[i];
    if (tid < NC) b2s[tid] = b2[tid];
    __syncthreads();
    const int wid = tid >> 6, lane = tid & 63;
    const int row = blockIdx.x * 4 + wid;
    const ushort_t* hrow = hb + (size_t)row * NH;
    ushort_t* vrow = vb + (size_t)row * NH;
    const int yi = y[row];
    float d0 = 0, d1 = 0, d2 = 0, d3 = 0, d4 = 0;
#pragma unroll
    for (int it = 0; it < 2; ++it) {
        const int n0 = it * 512 + lane * 8;
        u16x8 hv = *(const u16x8*)(hrow + n0);
        u16x8 ov;
#pragma unroll
        for (int j = 0; j < 8; ++j) {
            float hh = b2f(hv[j]);
            const float* wrow = &w2s[(n0 + j) * NC];
            d0 += hh * wrow[0]; d1 += hh * wrow[1]; d2 += hh * wrow[2];
            d3 += hh * wrow[3]; d4 += hh * wrow[4];
            ov[j] = f2b((1.f - hh * hh) * wrow[yi]);
        }
        *(u16x8*)(vrow + n0) = ov;
    }
#pragma unroll
    for (int off = 32; off; off >>= 1) {
        d0 += __shfl_xor(d0, off); d1 += __shfl_xor(d1, off); d2 += __shfl_xor(d2, off);
        d3 += __shfl_xor(d3, off); d4 += __shfl_xor(d4, off);
    }
    if (lane == 0) {
        float lg[NC] = { d0 + b2s[0], d1 + b2s[1], d2 + b2s[2], d3 + b2s[3], d4 + b2s[4] };
        float zy = lg[yi];
        float mse = 0.f, marg = 0.f;
        int amax = 0; float best = lg[0];
#pragma unroll
        for (int c = 0; c < NC; ++c) {
            float t = lg[c] - (c == yi ? 1.f : 0.f);
            mse += t * t;
            if (c != yi) marg += fmaxf(1.f - zy + lg[c], 0.f);
            if (lg[c] > best) { best = lg[c]; amax = c; }
        }
        rowstats[row] = make_float4(zy, mse, marg, (amax == yi) ? 1.f : 0.f);
    }
}

// ---------------- reductions ----------------
__global__ __launch_bounds__(256) void reduce_rows(const float4* __restrict__ rs,
                                                   const float* __restrict__ part,
                                                   int NT, float4* __restrict__ bsums) {
    const int tid = threadIdx.x;
    const int r = blockIdx.x * 256 + tid;
    float4 v = rs[r];
    float wl1 = 0.f;
    for (int t = 0; t < NT; ++t) wl1 += part[(size_t)t * NB + r];
    float R = wl1 * EPS_C / (fabsf(v.x) + 1e-8f);
    float4 s = make_float4(v.y, v.z, v.w, log1pf(R));
#pragma unroll
    for (int off = 32; off; off >>= 1) {
        s.x += __shfl_down(s.x, off); s.y += __shfl_down(s.y, off);
        s.z += __shfl_down(s.z, off); s.w += __shfl_down(s.w, off);
    }
    __shared__ float4 red[4];
    if ((tid & 63) == 0) red[tid >> 6] = s;
    __syncthreads();
    if (tid == 0) {
        float4 t = red[0];
        for (int i = 1; i < 4; ++i) { t.x += red[i].x; t.y += red[i].y; t.z += red[i].z; t.w += red[i].w; }
        bsums[blockIdx.x] = t;
    }
}

__global__ void final_combine(const float4* __restrict__ bsums, int nb, float* __restrict__ out) {
    if (threadIdx.x == 0) {
        float mse = 0, marg = 0, corr = 0, nsr = 0;
        for (int i = 0; i < nb; ++i) {
            float4 s = bsums[i];
            mse += s.x; marg += s.y; corr += s.z; nsr += s.w;
        }
        const float Bf = (float)NB;
        out[0] = mse / (Bf * (float)NC) + (marg / Bf + BETA * nsr / Bf) * (corr / Bf);
    }
}

extern "C" void kernel_launch(void* const* d_in, const int* in_sizes, int n_in,
                              void* d_out, int out_size, void* d_ws, size_t ws_size,
                              hipStream_t stream) {
    const float* x  = (const float*)d_in[0];
    const int*   y  = (const int*)d_in[1];
    const float* W1 = (const float*)d_in[2];
    const float* b1 = (const float*)d_in[3];
    const float* W2 = (const float*)d_in[4];
    const float* b2 = (const float*)d_in[5];
    float* out = (float*)d_out;

    char* ws = (char*)d_ws;
    ushort_t* W1Tb = (ushort_t*)(ws);                           // 4MB
    ushort_t* W1b  = (ushort_t*)(ws + (4ul << 20));             // 4MB
    ushort_t* xb   = (ushort_t*)(ws + (8ul << 20));             // 32MB
    ushort_t* hb   = (ushort_t*)(ws + (40ul << 20));            // 16MB
    ushort_t* vb   = (ushort_t*)(ws + (56ul << 20));            // 16MB
    float4*   rowstats = (float4*)(ws + (72ul << 20));          // 128KB
    float*    part = (float*)(ws + (72ul << 20) + (1ul << 20)); // 256KB
    float4*   bsums = (float4*)(ws + (74ul << 20));             // 512B

    // 1. conversions
    cvt_kernel<<<(NB * (long)NL) / (256 * 8), 256, 0, stream>>>(x, xb, (long)NB * NL);
    cvt_kernel<<<(NL * (long)NH) / (256 * 8), 256, 0, stream>>>(W1, W1b, (long)NL * NH);
    trans_kernel<<<dim3(NL / 32, NH / 32), 256, 0, stream>>>(W1, W1Tb);

    // 2. GEMM1 (round-3 proven): h = tanh(x @ W1 + b1)  [8192x1024]
    gemm8p<0><<<256, 512, 0, stream>>>(xb, W1Tb, b1, hb, nullptr);

    // 3. per-row: logits/mse/margin/zy/correct + v
    rows_kernel<<<NB / 4, 256, 0, stream>>>(hb, y, W2, b2, vb, rowstats);

    // 4. GEMM2 (new ring schedule): g = v @ W1^T, row |.| partials  [8192x2048]
    gemm2_ring<<<256, 512, 0, stream>>>(vb, W1b, part);

    // 5. reductions
    reduce_rows<<<NB / 256, 256, 0, stream>>>(rowstats, part, NL / 256, bsums);
    final_combine<<<1, 64, 0, stream>>>(bsums, NB / 256, out);
}

// Round 6
// 144.057 us; speedup vs baseline: 1.2794x; 1.0002x over previous
//
#include <hip/hip_runtime.h>
#include <hip/hip_bf16.h>

typedef unsigned short ushort_t;
typedef __attribute__((ext_vector_type(8))) short short8;
typedef __attribute__((ext_vector_type(8))) unsigned short u16x8;
typedef __attribute__((ext_vector_type(4))) float f32x4;

#define BETA 0.4f
#define EPS_C 0.05f
#define NB 8192
#define NH 1024
#define NL 2048
#define NC 5

static __device__ __forceinline__ float b2f(unsigned short u) {
    union { unsigned int i; float f; } x; x.i = ((unsigned int)u) << 16; return x.f;
}
static __device__ __forceinline__ unsigned short f2b(float f) {
    union { float f; unsigned int i; } x; x.f = f;
    unsigned int i = x.i;
    unsigned int r = (i + 0x7FFFu + ((i >> 16) & 1u)) >> 16;
    return (unsigned short)r;
}

static __device__ __forceinline__ void gload16(const ushort_t* g, ushort_t* l) {
    __builtin_amdgcn_global_load_lds((const __attribute__((address_space(1))) void*)g,
                                     (__attribute__((address_space(3))) void*)l, 16, 0, 0);
}

#define CFENCE() asm volatile("" ::: "memory")
#define MFMA16(d, a, b) __builtin_amdgcn_mfma_f32_16x16x32_bf16(a, b, d, 0, 0, 0)

// ---------------- conversion kernels ----------------
__global__ __launch_bounds__(256) void cvt_kernel(const float* __restrict__ in,
                                                  ushort_t* __restrict__ out, long n) {
    long i = ((long)blockIdx.x * 256 + threadIdx.x) * 8;
    if (i >= n) return;
    const float4 a = *(const float4*)(in + i);
    const float4 b = *(const float4*)(in + i + 4);
    u16x8 o;
    o[0] = f2b(a.x); o[1] = f2b(a.y); o[2] = f2b(a.z); o[3] = f2b(a.w);
    o[4] = f2b(b.x); o[5] = f2b(b.y); o[6] = f2b(b.z); o[7] = f2b(b.w);
    *(u16x8*)(out + i) = o;
}

// W1 [2048,1024] -> W1T bf16 [1024,2048]
__global__ __launch_bounds__(256) void trans_kernel(const float* __restrict__ W1,
                                                    ushort_t* __restrict__ W1Tb) {
    __shared__ float tile[32][33];
    const int tx = threadIdx.x & 31, ty = threadIdx.x >> 5;
    const int k0 = blockIdx.x * 32, n0 = blockIdx.y * 32;
#pragma unroll
    for (int i = 0; i < 4; ++i)
        tile[ty + i * 8][tx] = W1[(size_t)(k0 + ty + i * 8) * NH + n0 + tx];
    __syncthreads();
#pragma unroll
    for (int i = 0; i < 4; ++i)
        W1Tb[(size_t)(n0 + ty + i * 8) * NL + k0 + tx] = f2b(tile[tx][ty + i * 8]);
}

// ---------------- GEMM1: round-3 proven structure (gemm8p<0>) ----------------
template <int EPI>
__global__ __launch_bounds__(512, 2) void gemm8p(const ushort_t* __restrict__ A,
                                                 const ushort_t* __restrict__ Bt,
                                                 const float* __restrict__ b1,
                                                 ushort_t* __restrict__ hout,
                                                 float* __restrict__ partout) {
    constexpr int BN_T = (EPI == 0) ? 128 : 256;
    constexpr int K    = (EPI == 0) ? 2048 : 1024;
    constexpr int NOUT = (EPI == 0) ? 1024 : 2048;
    constexpr int NT   = K / 64;
    constexpr int NPH  = (EPI == 0) ? 2 : 4;
    constexpr int MPP  = 8 / NPH;
    constexpr int NREP = BN_T / 64;

    __shared__ ushort_t As[2][16384];
    __shared__ ushort_t Bs[2][BN_T * 64];

    const int tid = threadIdx.x;
    const int wv = tid >> 6, lane = tid & 63;
    const int wm = wv >> 2, wn = wv & 3;
    const int fr = lane & 15, fg = lane >> 4;
    const int swz = (lane & 7) << 4;
    const int cbb = fg << 4;

    const int xcd = blockIdx.x & 7, loc = blockIdx.x >> 3;
    const int bm0 = (xcd * 4 + (loc >> 3)) * 256;
    const int bnIdx = loc & 7;
    const int bn0 = bnIdx * BN_T;

    const int srow = lane >> 3;
    const int scol = ((lane & 7) ^ srow) << 3;

    auto stA = [&](int buf, int kt, int half) {
#pragma unroll
        for (int c = 0; c < 2; ++c) {
            const int row = wv * 16 + c * 8 + srow;
            gload16(A + (size_t)(bm0 + half * 128 + row) * K + kt * 64 + scol,
                    &As[buf][half * 8192 + wv * 1024 + c * 512]);
        }
    };
    auto stB = [&](int buf, int kt, int half) {
#pragma unroll
        for (int c = 0; c < 2; ++c) {
            const int row = wv * 16 + c * 8 + srow;
            gload16(Bt + (size_t)(bn0 + half * 128 + row) * K + kt * 64 + scol,
                    &Bs[buf][half * 8192 + wv * 1024 + c * 512]);
        }
    };
    auto ldA = [&](int buf, int mf, int ks) -> short8 {
        const int rowt = wm * 128 + mf * 16 + fr;
        return *(const short8*)((const char*)&As[buf][0] + rowt * 128 + (((ks << 6) + cbb) ^ swz));
    };
    auto ldB = [&](int buf, int nf, int ks) -> short8 {
        const int rowt = wn * (BN_T / 4) + nf * 16 + fr;
        return *(const short8*)((const char*)&Bs[buf][0] + rowt * 128 + (((ks << 6) + cbb) ^ swz));
    };

    f32x4 acc[8][NREP] = {};

    stA(0, 0, 0); stA(0, 0, 1);
    stB(0, 0, 0);
    if constexpr (EPI == 1) stB(0, 0, 1);
    asm volatile("s_waitcnt vmcnt(0)" ::: "memory");
    CFENCE(); __builtin_amdgcn_s_barrier(); CFENCE();

#define TILEBODY(BUF, TT)                                                          \
    {                                                                              \
        const int ttv = (TT);                                                      \
        const bool more = ttv + 1 < NT;                                            \
        short8 bfl[NREP][2];                                                       \
        _Pragma("unroll")                                                          \
        for (int n = 0; n < NREP; ++n) {                                           \
            bfl[n][0] = ldB(BUF, n, 0);                                            \
            bfl[n][1] = ldB(BUF, n, 1);                                            \
        }                                                                          \
        _Pragma("unroll")                                                          \
        for (int p = 0; p < NPH; ++p) {                                            \
            short8 af[MPP][2];                                                     \
            _Pragma("unroll")                                                      \
            for (int i = 0; i < MPP; ++i) {                                        \
                af[i][0] = ldA(BUF, p * MPP + i, 0);                               \
                af[i][1] = ldA(BUF, p * MPP + i, 1);                               \
            }                                                                      \
            if (p == 0 && more) {                                                  \
                stA(BUF ^ 1, ttv + 1, 0);                                          \
                stA(BUF ^ 1, ttv + 1, 1);                                          \
                if constexpr (EPI == 0) stB(BUF ^ 1, ttv + 1, 0);                  \
            }                                                                      \
            if constexpr (EPI == 1)                                                \
                if (p == 1 && more) {                                              \
                    stB(BUF ^ 1, ttv + 1, 0);                                      \
                    stB(BUF ^ 1, ttv + 1, 1);                                      \
                }                                                                  \
            CFENCE(); __builtin_amdgcn_s_barrier(); CFENCE();                      \
            __builtin_amdgcn_s_setprio(1);                                         \
            _Pragma("unroll")                                                      \
            for (int i = 0; i < MPP; ++i) {                                        \
                _Pragma("unroll")                                                  \
                for (int n = 0; n < NREP; ++n) {                                   \
                    acc[p * MPP + i][n] = __builtin_amdgcn_mfma_f32_16x16x32_bf16( \
                        af[i][0], bfl[n][0], acc[p * MPP + i][n], 0, 0, 0);        \
                    acc[p * MPP + i][n] = __builtin_amdgcn_mfma_f32_16x16x32_bf16( \
                        af[i][1], bfl[n][1], acc[p * MPP + i][n], 0, 0, 0);        \
                }                                                                  \
            }                                                                      \
            __builtin_amdgcn_s_setprio(0);                                         \
            if (p == NPH - 1) asm volatile("s_waitcnt vmcnt(0)" ::: "memory");     \
            CFENCE(); __builtin_amdgcn_s_barrier(); CFENCE();                      \
        }                                                                          \
    }

#pragma unroll 1
    for (int t = 0; t < NT; t += 2) {
        TILEBODY(0, t)
        TILEBODY(1, t + 1)
    }
#undef TILEBODY

    if constexpr (EPI == 0) {
#pragma unroll
        for (int m = 0; m < 8; ++m)
#pragma unroll
            for (int n = 0; n < NREP; ++n) {
                const int col = bn0 + wn * 32 + n * 16 + fr;
                const float bb = b1[col];
                const size_t rbase = (size_t)(bm0 + wm * 128 + m * 16 + fg * 4) * NOUT + col;
#pragma unroll
                for (int r = 0; r < 4; ++r)
                    hout[rbase + (size_t)r * NOUT] = f2b(tanhf(acc[m][n][r] + bb));
            }
    } else {
        float* rsum = (float*)&As[0][0];
#pragma unroll
        for (int m = 0; m < 8; ++m)
#pragma unroll
            for (int r = 0; r < 4; ++r) {
                float s = 0.f;
#pragma unroll
                for (int n = 0; n < NREP; ++n) s += fabsf(acc[m][n][r]);
                s += __shfl_xor(s, 1); s += __shfl_xor(s, 2);
                s += __shfl_xor(s, 4); s += __shfl_xor(s, 8);
                if (fr == 0) rsum[wn * 256 + wm * 128 + m * 16 + fg * 4 + r] = s;
            }
        __syncthreads();
        if (tid < 256)
            partout[(size_t)bnIdx * NB + bm0 + tid] =
                rsum[tid] + rsum[256 + tid] + rsum[512 + tid] + rsum[768 + tid];
    }
}

// ---------------- GEMM2 v2: ring schedule, uniform-dst staging, typed-GEP LDS ----------------
// A [8192,1024] bf16, Bt [2048,1024] bf16. Per-row |.| partials out.
// As[buf]: 256 rows x 64k, 128B rows, XOR-swizzled 16B slots (slot s holds logical s^(r&7)).
// Bs[buf]: two 32-k halves; half kh: 128 pair-rows (r1=n>>1) x 8 slots; slot p holds
//          logical sl=p^(r1&7), sl=((n&1)<<2)|kchunk.
__global__ __launch_bounds__(512, 2) void gemm2_ring(const ushort_t* __restrict__ A,
                                                     const ushort_t* __restrict__ Bt,
                                                     float* __restrict__ partout) {
    constexpr int NT = 16;
    __shared__ ushort_t As[2][16384];
    __shared__ ushort_t Bs[2][16384];

    const int tid = threadIdx.x;
    const int wv = tid >> 6, lane = tid & 63;
    const int wm = wv >> 2, wn = wv & 3;       // wave tile 128(M) x 64(N)
    const int fr = lane & 15, fg = lane >> 4;
    const int xcd = blockIdx.x & 7, loc = blockIdx.x >> 3;
    const int bm0 = (xcd * 4 + (loc >> 3)) * 256;
    const int bnIdx = loc & 7;
    const int bn0 = bnIdx * 256;

    // staging: LDS dst is WAVE-UNIFORM (hw appends lane*16B); source per-lane pre-swizzled
#define G2_STAGE_A(BUFN, KT) {                                                     \
    _Pragma("unroll") for (int j = 0; j < 4; ++j) {                                \
        const int r_ = j * 64 + wv * 8 + (lane >> 3);                              \
        const int kc_ = ((lane & 7) ^ (r_ & 7)) << 3;                              \
        gload16(A + (size_t)(bm0 + r_) * 1024 + (KT) * 64 + kc_,                   \
                &As[BUFN][j * 4096 + wv * 512]);                                   \
    } }
#define G2_STAGE_B(BUFN, KT) {                                                     \
    _Pragma("unroll") for (int j = 0; j < 4; ++j) {                                \
        const int kh_ = j >> 1;                                                    \
        const int r1_ = (j & 1) * 64 + wv * 8 + (lane >> 3);                       \
        const int sl_ = (lane & 7) ^ (r1_ & 7);                                    \
        const int n_ = r1_ * 2 + (sl_ >> 2);                                       \
        const int kc_ = kh_ * 32 + ((sl_ & 3) << 3);                               \
        gload16(Bt + (size_t)(bn0 + n_) * 1024 + (KT) * 64 + kc_,                  \
                &Bs[BUFN][j * 4096 + wv * 512]);                                   \
    } }

    auto ldA = [&](int buf, int mf, int ks) -> short8 {
        const int row = wm * 128 + mf * 16 + fr;
        const int el = row * 64 + ((((ks << 2) + fg) ^ (row & 7)) << 3);
        return *(const short8*)&As[buf][el];
    };
    auto ldB = [&](int buf, int kh, int nf) -> short8 {
        const int n = wn * 64 + nf * 16 + fr;
        const int r1 = n >> 1;
        const int p = (((n & 1) << 2) | fg) ^ (r1 & 7);
        return *(const short8*)&Bs[buf][kh * 8192 + r1 * 64 + p * 8];
    };

    f32x4 acc[8][4] = {};

    // prologue: stage tile 0, full drain once
    G2_STAGE_A(0, 0)
    G2_STAGE_B(0, 0)
    asm volatile("s_waitcnt vmcnt(0)" ::: "memory");

#define G2_RTILE(BUF, BUFN, TT) {                                                  \
    const int t_ = (TT);                                                           \
    const bool more = (t_ + 1 < NT);                                               \
    short8 af[8], ba[2], bb[2];                                                    \
    /* p0: BAR; reads af(ks0)+B(kh0,n01); stage A(t+1)+B(t+1); MFMA */             \
    CFENCE(); __builtin_amdgcn_s_barrier(); CFENCE();                              \
    _Pragma("unroll") for (int m = 0; m < 8; ++m) af[m] = ldA(BUF, m, 0);          \
    ba[0] = ldB(BUF, 0, 0); ba[1] = ldB(BUF, 0, 1);                                \
    if (more) { G2_STAGE_A(BUFN, t_ + 1) G2_STAGE_B(BUFN, t_ + 1) }                \
    __builtin_amdgcn_s_setprio(1);                                                 \
    _Pragma("unroll") for (int m = 0; m < 8; ++m) {                                \
        acc[m][0] = MFMA16(acc[m][0], af[m], ba[0]);                               \
        acc[m][1] = MFMA16(acc[m][1], af[m], ba[1]);                               \
    }                                                                              \
    __builtin_amdgcn_s_setprio(0);                                                 \
    /* p1: BAR; reads B(kh0,n23); MFMA */                                          \
    CFENCE(); __builtin_amdgcn_s_barrier(); CFENCE();                              \
    bb[0] = ldB(BUF, 0, 2); bb[1] = ldB(BUF, 0, 3);                                \
    __builtin_amdgcn_s_setprio(1);                                                 \
    _Pragma("unroll") for (int m = 0; m < 8; ++m) {                                \
        acc[m][2] = MFMA16(acc[m][2], af[m], bb[0]);                               \
        acc[m][3] = MFMA16(acc[m][3], af[m], bb[1]);                               \
    }                                                                              \
    __builtin_amdgcn_s_setprio(0);                                                 \
    /* p2: BAR; reads af(ks1)+B(kh1,n01); MFMA */                                  \
    CFENCE(); __builtin_amdgcn_s_barrier(); CFENCE();                              \
    _Pragma("unroll") for (int m = 0; m < 8; ++m) af[m] = ldA(BUF, m, 1);          \
    ba[0] = ldB(BUF, 1, 0); ba[1] = ldB(BUF, 1, 1);                                \
    __builtin_amdgcn_s_setprio(1);                                                 \
    _Pragma("unroll") for (int m = 0; m < 8; ++m) {                                \
        acc[m][0] = MFMA16(acc[m][0], af[m], ba[0]);                               \
        acc[m][1] = MFMA16(acc[m][1], af[m], ba[1]);                               \
    }                                                                              \
    __builtin_amdgcn_s_setprio(0);                                                 \
    /* p3: BAR; reads B(kh1,n23); MFMA; counted drain of 3-phase-old loads */      \
    CFENCE(); __builtin_amdgcn_s_barrier(); CFENCE();                              \
    bb[0] = ldB(BUF, 1, 2); bb[1] = ldB(BUF, 1, 3);                                \
    __builtin_amdgcn_s_setprio(1);                                                 \
    _Pragma("unroll") for (int m = 0; m < 8; ++m) {                                \
        acc[m][2] = MFMA16(acc[m][2], af[m], bb[0]);                               \
        acc[m][3] = MFMA16(acc[m][3], af[m], bb[1]);                               \
    }                                                                              \
    __builtin_amdgcn_s_setprio(0);                                                 \
    asm volatile("s_waitcnt vmcnt(0)" ::: "memory");                               \
    }

#pragma unroll 1
    for (int t = 0; t < NT; t += 2) {
        G2_RTILE(0, 1, t)
        G2_RTILE(1, 0, t + 1)
    }
#undef G2_RTILE
#undef G2_STAGE_A
#undef G2_STAGE_B

    // epilogue: per-row |.| partial sums
    __syncthreads();
    float* rsum = (float*)&As[0][0];
#pragma unroll
    for (int m = 0; m < 8; ++m)
#pragma unroll
        for (int r = 0; r < 4; ++r) {
            float s = 0.f;
#pragma unroll
            for (int n = 0; n < 4; ++n) s += fabsf(acc[m][n][r]);
            s += __shfl_xor(s, 1); s += __shfl_xor(s, 2);
            s += __shfl_xor(s, 4); s += __shfl_xor(s, 8);
            if (fr == 0) rsum[wn * 256 + wm * 128 + m * 16 + fg * 4 + r] = s;
        }
    __syncthreads();
    if (tid < 256)
        partout[(size_t)bnIdx * NB + bm0 + tid] =
            rsum[tid] + rsum[256 + tid] + rsum[512 + tid] + rsum[768 + tid];
}

// ---------------- per-row kernel: logits, losses, v ----------------
__global__ __launch_bounds__(256) void rows_kernel(const ushort_t* __restrict__ hb,
                                                   const int* __restrict__ y,
                                                   const float* __restrict__ W2,
                                                   const float* __restrict__ b2,
                                                   ushort_t* __restrict__ vb,
                                                   float4* __restrict__ rowstats) {
    __shared__ float w2s[NH * NC];
    __shared__ float b2s[NC];
    const int tid = threadIdx.x;
    for (int i = tid; i < NH * NC; i += 256) w2s[i] = W2[i];
    if (tid < NC) b2s[tid] = b2[tid];
    __syncthreads();
    const int wid = tid >> 6, lane = tid & 63;
    const int row = blockIdx.x * 4 + wid;
    const ushort_t* hrow = hb + (size_t)row * NH;
    ushort_t* vrow = vb + (size_t)row * NH;
    const int yi = y[row];
    float d0 = 0, d1 = 0, d2 = 0, d3 = 0, d4 = 0;
#pragma unroll
    for (int it = 0; it < 2; ++it) {
        const int n0 = it * 512 + lane * 8;
        u16x8 hv = *(const u16x8*)(hrow + n0);
        u16x8 ov;
#pragma unroll
        for (int j = 0; j < 8; ++j) {
            float hh = b2f(hv[j]);
            const float* wrow = &w2s[(n0 + j) * NC];
            d0 += hh * wrow[0]; d1 += hh * wrow[1]; d2 += hh * wrow[2];
            d3 += hh * wrow[3]; d4 += hh * wrow[4];
            ov[j] = f2b((1.f - hh * hh) * wrow[yi]);
        }
        *(u16x8*)(vrow + n0) = ov;
    }
#pragma unroll
    for (int off = 32; off; off >>= 1) {
        d0 += __shfl_xor(d0, off); d1 += __shfl_xor(d1, off); d2 += __shfl_xor(d2, off);
        d3 += __shfl_xor(d3, off); d4 += __shfl_xor(d4, off);
    }
    if (lane == 0) {
        float lg[NC] = { d0 + b2s[0], d1 + b2s[1], d2 + b2s[2], d3 + b2s[3], d4 + b2s[4] };
        float zy = lg[yi];
        float mse = 0.f, marg = 0.f;
        int amax = 0; float best = lg[0];
#pragma unroll
        for (int c = 0; c < NC; ++c) {
            float t = lg[c] - (c == yi ? 1.f : 0.f);
            mse += t * t;
            if (c != yi) marg += fmaxf(1.f - zy + lg[c], 0.f);
            if (lg[c] > best) { best = lg[c]; amax = c; }
        }
        rowstats[row] = make_float4(zy, mse, marg, (amax == yi) ? 1.f : 0.f);
    }
}

// ---------------- reductions ----------------
__global__ __launch_bounds__(256) void reduce_rows(const float4* __restrict__ rs,
                                                   const float* __restrict__ part,
                                                   int NT, float4* __restrict__ bsums) {
    const int tid = threadIdx.x;
    const int r = blockIdx.x * 256 + tid;
    float4 v = rs[r];
    float wl1 = 0.f;
    for (int t = 0; t < NT; ++t) wl1 += part[(size_t)t * NB + r];
    float R = wl1 * EPS_C / (fabsf(v.x) + 1e-8f);
    float4 s = make_float4(v.y, v.z, v.w, log1pf(R));
#pragma unroll
    for (int off = 32; off; off >>= 1) {
        s.x += __shfl_down(s.x, off); s.y += __shfl_down(s.y, off);
        s.z += __shfl_down(s.z, off); s.w += __shfl_down(s.w, off);
    }
    __shared__ float4 red[4];
    if ((tid & 63) == 0) red[tid >> 6] = s;
    __syncthreads();
    if (tid == 0) {
        float4 t = red[0];
        for (int i = 1; i < 4; ++i) { t.x += red[i].x; t.y += red[i].y; t.z += red[i].z; t.w += red[i].w; }
        bsums[blockIdx.x] = t;
    }
}

__global__ void final_combine(const float4* __restrict__ bsums, int nb, float* __restrict__ out) {
    if (threadIdx.x == 0) {
        float mse = 0, marg = 0, corr = 0, nsr = 0;
        for (int i = 0; i < nb; ++i) {
            float4 s = bsums[i];
            mse += s.x; marg += s.y; corr += s.z; nsr += s.w;
        }
        const float Bf = (float)NB;
        out[0] = mse / (Bf * (float)NC) + (marg / Bf + BETA * nsr / Bf) * (corr / Bf);
    }
}

extern "C" void kernel_launch(void* const* d_in, const int* in_sizes, int n_in,
                              void* d_out, int out_size, void* d_ws, size_t ws_size,
                              hipStream_t stream) {
    const float* x  = (const float*)d_in[0];
    const int*   y  = (const int*)d_in[1];
    const float* W1 = (const float*)d_in[2];
    const float* b1 = (const float*)d_in[3];
    const float* W2 = (const float*)d_in[4];
    const float* b2 = (const float*)d_in[5];
    float* out = (float*)d_out;

    char* ws = (char*)d_ws;
    ushort_t* W1Tb = (ushort_t*)(ws);                           // 4MB
    ushort_t* W1b  = (ushort_t*)(ws + (4ul << 20));             // 4MB
    ushort_t* xb   = (ushort_t*)(ws + (8ul << 20));             // 32MB
    ushort_t* hb   = (ushort_t*)(ws + (40ul << 20));            // 16MB
    ushort_t* vb   = (ushort_t*)(ws + (56ul << 20));            // 16MB
    float4*   rowstats = (float4*)(ws + (72ul << 20));          // 128KB
    float*    part = (float*)(ws + (72ul << 20) + (1ul << 20)); // 256KB
    float4*   bsums = (float4*)(ws + (74ul << 20));             // 512B

    // 1. conversions
    cvt_kernel<<<(NB * (long)NL) / (256 * 8), 256, 0, stream>>>(x, xb, (long)NB * NL);
    cvt_kernel<<<(NL * (long)NH) / (256 * 8), 256, 0, stream>>>(W1, W1b, (long)NL * NH);
    trans_kernel<<<dim3(NL / 32, NH / 32), 256, 0, stream>>>(W1, W1Tb);

    // 2. GEMM1 (proven): h = tanh(x @ W1 + b1)  [8192x1024]
    gemm8p<0><<<256, 512, 0, stream>>>(xb, W1Tb, b1, hb, nullptr);

    // 3. per-row: logits/mse/margin/zy/correct + v
    rows_kernel<<<NB / 4, 256, 0, stream>>>(hb, y, W2, b2, vb, rowstats);

    // 4. GEMM2 (ring v2): g = v @ W1^T, row |.| partials  [8192x2048]
    gemm2_ring<<<256, 512, 0, stream>>>(vb, W1b, part);

    // 5. reductions
    reduce_rows<<<NB / 256, 256, 0, stream>>>(rowstats, part, NL / 256, bsums);
    final_combine<<<1, 64, 0, stream>>>(bsums, NB / 256, out);
}